// Round 1
// baseline (243.581 us; speedup 1.0000x reference)
//
#include <hip/hip_runtime.h>
#include <math.h>

// NoisyTopkRouter: B=8,S=4096,D=1024,E=64,k=2  (M=32768 tokens)
// R6: all staging via global_load_lds.
//  - prep_B: pre-split Wl|Wn (128x1024 f32) into fp16 hi/lo 32-K-tile images in d_ws,
//    XOR-swizzled per row (chunk c -> c^(r&7)) so the main kernel stages them with
//    LINEAR global_load_lds and reads ds_read_b128 fragments conflict-free.
//  - main kernel: A staged as raw fp32 via global_load_lds with pre-swizzled per-lane
//    GLOBAL source address (LDS dest linear); fp32->fp16 hi/lo split happens at
//    fragment-read time in registers. Zero ds_writes, zero staging VALU for B.
//  - dbuf, prefetch distance = 1 full compute phase; __syncthreads() == the exact
//    vmcnt(0)+lgkmcnt(0)+barrier the schedule needs.
//  - fp16x3 MFMA math (C = Ah*Bh + (Ah*Bl + Al*Bh)/2048) and epilogue unchanged
//    (verified R1-R5); accumulation order identical -> bit-identical outputs.

#define DIM 1024
#define NEXP 64
#define CS 132
#define LOSCALE 2048.0f
#define INV_LOSCALE (1.0f / 2048.0f)

using half8v   = __attribute__((ext_vector_type(8)))  _Float16;
using floatx16 = __attribute__((ext_vector_type(16))) float;

#define MFMA32(a, b, c) __builtin_amdgcn_mfma_f32_32x32x16_f16((a), (b), (c), 0, 0, 0)

__device__ inline void gll16(const void* g, void* l) {
    __builtin_amdgcn_global_load_lds(
        (const __attribute__((address_space(1))) unsigned int*)g,
        (__attribute__((address_space(3))) unsigned int*)l, 16, 0, 0);
}

// ---------------- prep: split weights to fp16 hi/lo, swizzled tile images ----------
__global__ __launch_bounds__(512)
void prep_B(const float* __restrict__ Wl, const float* __restrict__ Wn,
            _Float16* __restrict__ Bp)
{
    const int idx = blockIdx.x * 512 + threadIdx.x;   // 16384 threads
    const int r  = idx >> 7;        // expert row 0..127 (0..63 = Wl, 64..127 = Wn)
    const int c2 = idx & 127;       // 8-float chunk across K=1024
    const float* W = (r < 64) ? (Wl + (size_t)r * DIM) : (Wn + (size_t)(r - 64) * DIM);
    float f[8];
    *(float4*)(f)     = *(const float4*)(W + c2 * 8);
    *(float4*)(f + 4) = *(const float4*)(W + c2 * 8 + 4);
    half8v hi, lo;
#pragma unroll
    for (int i = 0; i < 8; i++) {
        _Float16 hh = (_Float16)f[i];
        hi[i] = hh;
        lo[i] = (_Float16)((f[i] - (float)hh) * LOSCALE);
    }
    const int t = c2 >> 2, cf = c2 & 3, sw = r & 7;
    // tile image: [t][r][8 chunks of 8 halves], chunk index XOR-swizzled by row
    _Float16* base = Bp + ((size_t)t * 128 + r) * 64;
    *(half8v*)(base + ((cf ^ sw) << 3))      = hi;   // hi chunks 0..3
    *(half8v*)(base + (((4 | cf) ^ sw) << 3)) = lo;  // lo chunks 4..7
}

// ---------------- main fused kernel ------------------------------------------------
__global__ __launch_bounds__(512, 4)
void router_fused(const float* __restrict__ h, const _Float16* __restrict__ Bp,
                  const float* __restrict__ bl, const float* __restrict__ bn,
                  const float* __restrict__ noise,
                  float* __restrict__ outR, float* __restrict__ outIx,
                  float* __restrict__ outF)
{
    // LDS: [A0 8K][A1 8K][B0 16K][B1 16K] = 49152 B; Cs overlay needs 33792 B
    __shared__ __align__(16) char lds_raw[49152];

    const int tid   = threadIdx.x;           // 0..511
    const int wv    = tid >> 6;              // 0..7
    const int lane  = tid & 63;
    const int row31 = lane & 31;
    const int oct   = lane >> 5;
    const int tokg  = (wv >> 2) * 32;        // 0 or 32
    const int expg  = (wv & 3) * 32;         // 0,32,64,96
    const int tok0  = blockIdx.x * 64;

    // ---- staging: per-thread 16B, LDS dest linear, A source chunk-swizzled ----
    const int rS = tid >> 3, cS = tid & 7;
    const float*    aSrc = h + (size_t)(tok0 + rS) * DIM + ((cS ^ (rS & 7)) << 2);
    const _Float16* bSrc = Bp + (size_t)tid * 8;
    char* dA = lds_raw + (tid << 4);
    char* dB = lds_raw + 16384 + (tid << 4);

#define ISSUE(tt, sel) do { \
        gll16(aSrc + (tt) * 32,                  dA + (sel) * 8192);        \
        gll16(bSrc + (size_t)(tt) * 8192,        dB + (sel) * 16384);       \
        gll16(bSrc + (size_t)(tt) * 8192 + 4096, dB + (sel) * 16384 + 8192);\
    } while (0)

    // ---- fragment addressing (128B rows, 16B-chunk XOR swizzle) ----
    const int rA = tokg + row31, rB = expg + row31;
    const int swA = (rA & 7) << 4, swB = (rB & 7) << 4;
    const char* A0p = lds_raw + rA * 128;
    const char* A1p = A0p + 8192;
    const char* B0p = lds_raw + 16384 + rB * 128;
    const char* B1p = B0p + 16384;
    const int a00 = (oct * 32) ^ swA,      a01 = (oct * 32 + 16) ^ swA;
    const int a10 = (64 + oct * 32) ^ swA, a11 = (64 + oct * 32 + 16) ^ swA;
    const int bh0 = (oct * 16) ^ swB,      bh1 = (32 + oct * 16) ^ swB;
    const int bl0 = (64 + oct * 16) ^ swB, bl1 = (96 + oct * 16) ^ swB;

    floatx16 acc1, acc2;
#pragma unroll
    for (int i = 0; i < 16; i++) { acc1[i] = 0.f; acc2[i] = 0.f; }

    // ---- prologue: tiles 0,1 in flight ----
    ISSUE(0, 0);
    ISSUE(1, 1);
    __syncthreads();                         // drains vmcnt(0): tile0 (and 1) landed

    // ---- K loop: compute tile t; barrier waits tile t+1; then issue tile t+2 ----
#pragma unroll 2
    for (int t = 0; t < 32; t++) {
        const char* Ab = (t & 1) ? A1p : A0p;
        const char* Bb = (t & 1) ? B1p : B0p;
#pragma unroll
        for (int ks = 0; ks < 2; ks++) {
            const float4 f0 = *(const float4*)(Ab + (ks ? a10 : a00));
            const float4 f1 = *(const float4*)(Ab + (ks ? a11 : a01));
            const half8v bH = *(const half8v*)(Bb + (ks ? bh1 : bh0));
            const half8v bL = *(const half8v*)(Bb + (ks ? bl1 : bl0));
            float f[8] = {f0.x, f0.y, f0.z, f0.w, f1.x, f1.y, f1.z, f1.w};
            half8v aH, aL;
#pragma unroll
            for (int i = 0; i < 8; i++) {
                _Float16 hh = (_Float16)f[i];
                aH[i] = hh;
                aL[i] = (_Float16)((f[i] - (float)hh) * LOSCALE);
            }
            acc1 = MFMA32(aH, bH, acc1);
            acc2 = MFMA32(aH, bL, acc2);
            acc2 = MFMA32(aL, bH, acc2);
        }
        __syncthreads();                     // vmcnt(0): tile t+1 landed; reads done
        if (t < 30) ISSUE(t + 2, t & 1);     // into just-freed buffer
    }
#undef ISSUE

    // ---- Cs overlay: C layout col=lane&31, row=(reg&3)+8*(reg>>2)+4*oct ----
    float* Cs = (float*)lds_raw;
#pragma unroll
    for (int i = 0; i < 16; i++) {
        int rowt = (i & 3) + 8 * (i >> 2) + 4 * oct;
        Cs[(tokg + rowt) * CS + expg + row31] = acc1[i] + acc2[i] * INV_LOSCALE;
    }
    __syncthreads();

    // ---- fused epilogue: one wave per token, lane = expert (verified R1-R5) ----
    const float blv = bl[lane];
    const float bnv = bn[lane];

    for (int t = wv; t < 64; t += 8) {
        const int gt = tok0 + t;
        float xr = Cs[t * CS + lane] + blv;
        float xf = Cs[t * CS + 64 + lane] + bnv;
        float nz = noise[(size_t)gt * NEXP + lane];

        // softplus (matches jax.nn.softplus)
        float stdv = fmaxf(xf, 0.f) + log1pf(expf(-fabsf(xf)));
        float noisy = fmaf(nz, stdv, xr);

        // full softmax over 64 lanes
        float m = noisy;
#pragma unroll
        for (int o = 32; o > 0; o >>= 1) m = fmaxf(m, __shfl_xor(m, o, 64));
        float p = expf(noisy - m);
        float s = p;
#pragma unroll
        for (int o = 32; o > 0; o >>= 1) s += __shfl_xor(s, o, 64);
        float fullp = p / s;

        // argmax #1 (ties -> lowest index, matching lax.top_k)
        float v = noisy; int idx = lane;
#pragma unroll
        for (int o = 32; o > 0; o >>= 1) {
            float ov = __shfl_xor(v, o, 64);
            int   oi = __shfl_xor(idx, o, 64);
            if (ov > v || (ov == v && oi < idx)) { v = ov; idx = oi; }
        }
        const float v1 = v; const int i1 = idx;
        // argmax #2
        v = (lane == i1) ? -INFINITY : noisy; idx = lane;
#pragma unroll
        for (int o = 32; o > 0; o >>= 1) {
            float ov = __shfl_xor(v, o, 64);
            int   oi = __shfl_xor(idx, o, 64);
            if (ov > v || (ov == v && oi < idx)) { v = ov; idx = oi; }
        }
        const float v2 = v; const int i2 = idx;

        // sparse softmax over {i1,i2}
        float e2 = expf(v2 - v1);
        float den = 1.f + e2;
        float routep = (lane == i1) ? (1.f / den) : ((lane == i2) ? (e2 / den) : 0.f);

        outR[(size_t)gt * NEXP + lane] = routep;
        outF[(size_t)gt * NEXP + lane] = fullp;
        if (lane == 0) {
            outIx[(size_t)gt * 2 + 0] = (float)i1;
            outIx[(size_t)gt * 2 + 1] = (float)i2;
        }
    }
}

extern "C" void kernel_launch(void* const* d_in, const int* in_sizes, int n_in,
                              void* d_out, int out_size, void* d_ws, size_t ws_size,
                              hipStream_t stream) {
    const float* h     = (const float*)d_in[0];
    const float* Wl    = (const float*)d_in[1];
    const float* bl    = (const float*)d_in[2];
    const float* Wn    = (const float*)d_in[3];
    const float* bn    = (const float*)d_in[4];
    const float* noise = (const float*)d_in[5];
    float* out = (float*)d_out;

    const int M = in_sizes[0] / DIM;                 // 32768
    float* outR  = out;                              // [M,64]
    float* outIx = out + (size_t)M * NEXP;           // [M,2]
    float* outF  = outIx + (size_t)M * 2;            // [M,64]

    _Float16* Bp = (_Float16*)d_ws;                  // 512 KiB tile images

    prep_B<<<32, 512, 0, stream>>>(Wl, Wn, Bp);
    router_fused<<<M / 64, 512, 0, stream>>>(h, Bp, bl, bn, noise, outR, outIx, outF);
}